// Round 7
// baseline (431.090 us; speedup 1.0000x reference)
//
#include <hip/hip_runtime.h>

#define LOG2E 1.4426950408889634f
#define LN2   0.6931471805599453f

namespace {
constexpr int B    = 64;
constexpr int T    = 2000;
constexpr int V    = 256;
constexpr int S    = 400;
constexpr int CHK  = 8;                         // steps per handoff chunk
constexpr int NCT  = (T - 1 + CHK - 1) / CHK;   // 250 chunks
constexpr int BSTR = 12;                        // bnd floats per chunk
// pre-gathered prob matrix: G[b][k][i], k=0..399 tokens, k=400 blank,
// i = t-1 (so chunk c starts at i = 8c, 16B-aligned), fp16, row stride 2048
constexpr int TP = 2048;
constexpr int KR = 401;
constexpr size_t GBYTES = (size_t)B * KR * TP * 2;   // 105,119,744 B
// fallback (round-6) params
constexpr int NW7 = 7;
}

using h8 = __attribute__((ext_vector_type(8))) _Float16;   // 16 B

__device__ __forceinline__ float fexp2(float x){ return __builtin_amdgcn_exp2f(x); }
__device__ __forceinline__ float flog2(float x){ return __builtin_amdgcn_logf(x); }

__device__ __forceinline__ float wave_shr1(float x) {
  int v = __builtin_amdgcn_update_dpp(0, __builtin_bit_cast(int, x),
                                      0x138 /*WAVE_SHR1*/, 0xf, 0xf, true);
  return __builtin_bit_cast(float, v);
}

// ---------------- pre-gather pass: G[b][k][i] = fp16(exp(lp[b][i+1][col])) --
// Block = (tile of 64 i-values) x (batch). Stage 64 rows of lp in LDS with
// stride 257 (conflict-free column reads), then each wave (uniform k) reads
// column tg[k] across its 64 i-lanes and writes a contiguous fp16 run.
__global__ __launch_bounds__(256)
void ctc_gather_kernel(const float* __restrict__ logp,
                       const int* __restrict__ targets,
                       _Float16* __restrict__ G)
{
  const int tile = blockIdx.x;            // 32 tiles
  const int b    = blockIdx.y;
  const int tid  = threadIdx.x;
  const int i0   = tile * 64;
  const float* lp = logp + (size_t)b * T * V;
  const int*   tg = targets + (size_t)b * S;

  __shared__ float ls[64 * 257];          // 64.25 KB

  for (int f = tid; f < 64 * 64; f += 256) {
    const int row = f >> 6, c4 = f & 63;
    int t = i0 + 1 + row; if (t > T - 1) t = T - 1;
    float4 v = ((const float4*)(lp + (size_t)t * V))[c4];
    float* d = &ls[row * 257 + c4 * 4];
    d[0] = v.x; d[1] = v.y; d[2] = v.z; d[3] = v.w;
  }
  __syncthreads();

  const int tx = tid & 63, ty = tid >> 6;
  _Float16* gb = G + (size_t)b * KR * TP + i0 + tx;
  for (int k = ty; k < KR; k += 4) {      // k uniform per wave
    const int e = (k < S) ? tg[k] : 1;    // row 400 = blank
    const float p = fexp2(ls[tx * 257 + e] * LOG2E);
    gb[(size_t)k * TP] = (_Float16)p;
  }
}

// ---------------- main: 4 waves per chain, 4 states/lane, prob domain -------
__global__ __launch_bounds__(256)
void ctc_alpha4_kernel(const float* __restrict__ logp,
                       const int* __restrict__ targets,
                       const int* __restrict__ input_len,
                       const int* __restrict__ target_len,
                       const _Float16* __restrict__ G,
                       float* __restrict__ out)
{
  const int b    = blockIdx.x;
  const int tid  = threadIdx.x;
  const int w    = tid >> 6;
  const int lane = tid & 63;
  const bool lane0 = (lane == 0);
  const float* __restrict__ lp = logp + (size_t)b * T * V;
  const int il = input_len[b];
  const int tl = target_len[b];

  __shared__ float bnd[3][NCT * BSTR];    // 36 KB boundary streams
  __shared__ int   cnt[3];
  __shared__ float afin[1024];

  if (tid < 3) cnt[tid] = 0;

  // lane owns states {4g..4g+3}; tokens ka=2g (state 4g+1), kb=2g+1 (4g+3)
  const int* tg = targets + (size_t)b * S;
  int ka = 2 * tid;     if (ka > S - 1) ka = S - 1;
  int kb = 2 * tid + 1; if (kb > S - 1) kb = S - 1;
  const int ea = tg[ka];
  const int eb = tg[kb];
  const float ska = (ka == 0 || ea != tg[ka - 1]) ? 1.0f : 0.0f;
  const float skb = (eb != tg[kb - 1]) ? 1.0f : 0.0f;   // kb >= 1

  const _Float16* gA  = G + ((size_t)b * KR + ka)  * TP;
  const _Float16* gB  = G + ((size_t)b * KR + kb)  * TP;
  const _Float16* gBL = G + ((size_t)b * KR + 400) * TP;   // blank (broadcast)

  __syncthreads();   // cnt visible

  float a0 = 0.0f, a1 = 0.0f, a2 = 0.0f, a3 = 0.0f;
  int   E  = 0;
  if (tid == 0) {
    a0 = fexp2(lp[1]  * LOG2E);
    a1 = fexp2(lp[ea] * LOG2E);
  }

  // preload chunk 0 (16B per row)
  h8 ha = *(const h8*)gA;
  h8 hb = *(const h8*)gB;
  h8 hk = *(const h8*)gBL;

  const int NCH = (il - 1 + CHK - 1) / CHK;
  for (int c = 0; c < NCH; ++c) {
    // convert current chunk probs to fp32
    float pa[CHK], pb[CHK], pk[CHK];
    #pragma unroll
    for (int i = 0; i < CHK; ++i) {
      pa[i] = (float)ha[i]; pb[i] = (float)hb[i]; pk[i] = (float)hk[i];
    }
    // prefetch next chunk (stays inside padded row: (c+1)*8+7 <= 2007 < 2048)
    {
      const int in0 = (c + 1) * CHK;
      ha = *(const h8*)(gA  + in0);
      hb = *(const h8*)(gB  + in0);
      hk = *(const h8*)(gBL + in0);
    }

    // consume boundary chunk (values at t = 8c .. 8c+7, producer scale Ep)
    float bq[CHK];
    int Ep = 0;
    if (w > 0) {
      while (__hip_atomic_load(&cnt[w - 1], __ATOMIC_ACQUIRE,
                               __HIP_MEMORY_SCOPE_WORKGROUP) < c + 1)
        __builtin_amdgcn_s_sleep(1);
      const float* src = &bnd[w - 1][c * BSTR];
      float4 q0 = *(const float4*)(src);
      float4 q1 = *(const float4*)(src + 4);
      bq[0]=q0.x; bq[1]=q0.y; bq[2]=q0.z; bq[3]=q0.w;
      bq[4]=q1.x; bq[5]=q1.y; bq[6]=q1.z; bq[7]=q1.w;
      Ep = __float_as_int(src[8]);
    } else {
      #pragma unroll
      for (int i = 0; i < CHK; ++i) bq[i] = 0.0f;
    }

    // per-chunk exponent bookkeeping (front advances <= 2 lanes/chunk)
    const float mz  = fmaxf(fmaxf(a0, a1), fmaxf(a2, a3));
    const int   E1o = __shfl_up(E, 1);
    const int   E4  = __shfl_up(E, 4);
    const int   E5  = __shfl_up(E, 5);
    const float mz1 = __shfl_up(mz, 1);
    if (mz == 0.0f) E = (lane < 4) ? Ep : E4;            // pre-adopt scale
    int E1 = (mz1 == 0.0f) ? ((lane <= 4) ? Ep : E5) : E1o;
    if (lane0) E1 = (w == 0) ? E : Ep;
    int d = E1 - E; d = d > 126 ? 126 : (d < -126 ? -126 : d);
    const float f = ldexpf(1.0f, d);
    const float a3s = a3;                                // value at t0-1

    float pub[CHK];
    #pragma unroll
    for (int i = 0; i < CHK; ++i) {
      const int t = 1 + c * CHK + i;
      if (t < il) {                          // wave-uniform freeze predicate
        float hl = wave_shr1(a3);            // alpha[s0-1] from lane-1
        hl = lane0 ? bq[i] : hl;
        hl *= f;
        float t3 = a3 + a2;  a3 = __builtin_fmaf(a1, skb, t3) * pb[i];
        a2 = (a2 + a1) * pk[i];
        float t1 = a1 + a0;  a1 = __builtin_fmaf(hl, ska, t1) * pa[i];
        a0 = (a0 + hl) * pk[i];
      }
      pub[i] = a3;
    }

    // publish boundary (in this chunk's scale E) + release counter
    if (w < 3 && lane == 63) {
      float* dst = &bnd[w][c * BSTR];
      dst[0] = a3s;
      #pragma unroll
      for (int i = 0; i < CHK - 1; ++i) dst[1 + i] = pub[i];
      dst[8] = __int_as_float(E);
      __hip_atomic_store(&cnt[w], c + 1, __ATOMIC_RELEASE,
                         __HIP_MEMORY_SCOPE_WORKGROUP);
    }

    // renormalize per lane
    {
      float m2 = fmaxf(fmaxf(a0, a1), fmaxf(a2, a3));
      int k = 0;
      (void)frexpf(m2, &k);                  // m2==0 -> k=0
      a0 = ldexpf(a0, -k); a1 = ldexpf(a1, -k);
      a2 = ldexpf(a2, -k); a3 = ldexpf(a3, -k);
      E += k;
    }
  }

  afin[4 * tid + 0] = flog2(a0) + (float)E;
  afin[4 * tid + 1] = flog2(a1) + (float)E;
  afin[4 * tid + 2] = flog2(a2) + (float)E;
  afin[4 * tid + 3] = flog2(a3) + (float)E;
  __syncthreads();

  if (tid == 0) {
    const float x = afin[2 * tl];
    const float y = afin[2 * tl - 1];
    const float m = fmaxf(x, y);
    const float ll = (m + flog2(fexp2(x - m) + fexp2(y - m))) * LN2;
    float loss = -ll;
    if (!(loss < 1e29f)) loss = 0.0f;
    atomicAdd(out, loss / ((float)tl * (float)B));
  }
}

// ---------------- fallback: round-6 kernel (validated), used if ws too small
__global__ __launch_bounds__(NW7 * 64)
void ctc_alpha7_kernel(const float* __restrict__ logp,
                       const int* __restrict__ targets,
                       const int* __restrict__ input_len,
                       const int* __restrict__ target_len,
                       float* __restrict__ out)
{
  const int b    = blockIdx.x;
  const int tid  = threadIdx.x;
  const int w    = tid >> 6;
  const int lane = tid & 63;
  const bool lane0 = (lane == 0);
  const float* __restrict__ lp = logp + (size_t)b * T * V;
  const int il = input_len[b];
  const int tl = target_len[b];
  const int Lb = 2 * tl + 1;

  __shared__ float bnd[NW7 - 1][NCT * BSTR];
  __shared__ int   cnt[NW7 - 1];
  __shared__ float pblk[T];
  __shared__ float afin[NW7 * 64 * 2];

  if (tid < NW7 - 1) cnt[tid] = 0;

  const int* tg = targets + (size_t)b * S;
  const int k1 = (tid < S) ? tid : (S - 1);
  const int e1 = tg[k1];
  const float sk1 = (k1 == 0 || e1 != tg[k1 - 1]) ? 1.0f : 0.0f;

  for (int i = tid; i < T; i += NW7 * 64) {
    int t = (i + 1 < T) ? (i + 1) : (T - 1);
    pblk[i] = fexp2(lp[(size_t)t * V + 1] * LOG2E);
  }
  __syncthreads();

  const bool active = (w * 128) < Lb;
  if (active) {
    float a0 = 0.0f, a1 = 0.0f;
    int   E  = 0;
    if (tid == 0) { a0 = fexp2(lp[1] * LOG2E); a1 = fexp2(lp[e1] * LOG2E); }

    float tokL[CHK];
    #pragma unroll
    for (int i = 0; i < CHK; ++i) tokL[i] = lp[(size_t)(1 + i) * V + e1];

    const int NCH = (il - 1 + CHK - 1) / CHK;
    for (int c = 0; c < NCH; ++c) {
      const int t0 = 1 + c * CHK;
      float tokP[CHK];
      #pragma unroll
      for (int i = 0; i < CHK; ++i) tokP[i] = fexp2(tokL[i] * LOG2E);
      float nl[CHK];
      if (c + 1 < NCT) {
        #pragma unroll
        for (int i = 0; i < CHK; ++i) {
          int tt = t0 + CHK + i; if (tt > T - 1) tt = T - 1;
          nl[i] = lp[(size_t)tt * V + e1];
        }
      }
      float pbk[CHK];
      {
        float4 q0 = *(const float4*)&pblk[c * CHK];
        float4 q1 = *(const float4*)&pblk[c * CHK + 4];
        pbk[0]=q0.x; pbk[1]=q0.y; pbk[2]=q0.z; pbk[3]=q0.w;
        pbk[4]=q1.x; pbk[5]=q1.y; pbk[6]=q1.z; pbk[7]=q1.w;
      }
      float bq[CHK];
      int Ep = 0;
      if (w > 0) {
        while (__hip_atomic_load(&cnt[w - 1], __ATOMIC_ACQUIRE,
                                 __HIP_MEMORY_SCOPE_WORKGROUP) < c + 1)
          __builtin_amdgcn_s_sleep(1);
        const float* src = &bnd[w - 1][c * BSTR];
        float4 q0 = *(const float4*)(src);
        float4 q1 = *(const float4*)(src + 4);
        bq[0]=q0.x; bq[1]=q0.y; bq[2]=q0.z; bq[3]=q0.w;
        bq[4]=q1.x; bq[5]=q1.y; bq[6]=q1.z; bq[7]=q1.w;
        Ep = __float_as_int(src[8]);
      } else {
        #pragma unroll
        for (int i = 0; i < CHK; ++i) bq[i] = 0.0f;
      }
      const float mz  = fmaxf(a0, a1);
      const int   E1o = __shfl_up(E, 1);
      const int   E8  = __shfl_up(E, 8);
      const int   E9  = __shfl_up(E, 9);
      const float mz1 = __shfl_up(mz, 1);
      if (mz == 0.0f) E = (lane < 8) ? Ep : E8;
      int E1 = (mz1 == 0.0f) ? ((lane <= 8) ? Ep : E9) : E1o;
      if (lane0) E1 = (w == 0) ? E : Ep;
      int d = E1 - E; d = d > 126 ? 126 : (d < -126 ? -126 : d);
      const float f = ldexpf(1.0f, d);
      const float a1s = a1;
      float pub[CHK];
      #pragma unroll
      for (int i = 0; i < CHK; ++i) {
        const int t = t0 + i;
        if (t < il) {
          float hl = wave_shr1(a1);
          hl = lane0 ? bq[i] : hl;
          hl *= f;
          float s01 = a1 + a0;
          a1 = __builtin_fmaf(hl, sk1, s01) * tokP[i];
          a0 = (a0 + hl) * pbk[i];
        }
        pub[i] = a1;
      }
      if (w < NW7 - 1 && lane == 63) {
        float* dst = &bnd[w][c * BSTR];
        dst[0] = a1s;
        #pragma unroll
        for (int i = 0; i < CHK - 1; ++i) dst[1 + i] = pub[i];
        dst[8] = __int_as_float(E);
        __hip_atomic_store(&cnt[w], c + 1, __ATOMIC_RELEASE,
                           __HIP_MEMORY_SCOPE_WORKGROUP);
      }
      {
        float m2 = fmaxf(a0, a1);
        int k = 0;
        (void)frexpf(m2, &k);
        a0 = ldexpf(a0, -k);
        a1 = ldexpf(a1, -k);
        E += k;
      }
      #pragma unroll
      for (int i = 0; i < CHK; ++i) tokL[i] = nl[i];
    }
    afin[2 * tid]     = flog2(a0) + (float)E;
    afin[2 * tid + 1] = flog2(a1) + (float)E;
  }
  __syncthreads();

  if (tid == 0) {
    const float x = afin[2 * tl];
    const float y = afin[2 * tl - 1];
    const float m = fmaxf(x, y);
    const float ll = (m + flog2(fexp2(x - m) + fexp2(y - m))) * LN2;
    float loss = -ll;
    if (!(loss < 1e29f)) loss = 0.0f;
    atomicAdd(out, loss / ((float)tl * (float)B));
  }
}

__global__ void ctc_zero_kernel(float* __restrict__ out) { out[0] = 0.0f; }

extern "C" void kernel_launch(void* const* d_in, const int* in_sizes, int n_in,
                              void* d_out, int out_size, void* d_ws, size_t ws_size,
                              hipStream_t stream) {
  const float* logp    = (const float*)d_in[0];
  const int*   targets = (const int*)d_in[1];
  const int*   il      = (const int*)d_in[2];
  const int*   tl      = (const int*)d_in[3];
  float* out = (float*)d_out;

  ctc_zero_kernel<<<1, 1, 0, stream>>>(out);
  if (ws_size >= GBYTES) {
    _Float16* G = (_Float16*)d_ws;
    ctc_gather_kernel<<<dim3(32, B), 256, 0, stream>>>(logp, targets, G);
    ctc_alpha4_kernel<<<B, 256, 0, stream>>>(logp, targets, il, tl, G, out);
  } else {
    ctc_alpha7_kernel<<<B, NW7 * 64, 0, stream>>>(logp, targets, il, tl, out);
  }
}

// Round 8
// 370.652 us; speedup vs baseline: 1.1631x; 1.1631x over previous
//
#include <hip/hip_runtime.h>

#define LOG2E 1.4426950408889634f
#define LN2   0.6931471805599453f

namespace {
constexpr int B    = 64;
constexpr int T    = 2000;
constexpr int V    = 256;
constexpr int S    = 400;
constexpr int CHK  = 8;
constexpr int NCTP = 250;                       // chunks stored in G
constexpr int BSTR = 12;                        // bnd floats per chunk
constexpr int KP   = 408;                       // padded k rows (401 used)
// G[b][c][k][j]: fp16 prob of token-row k at t = 1 + c*8 + j
constexpr size_t GELEM  = (size_t)B * NCTP * KP * 8;
constexpr size_t GBYTES = GELEM * 2;            // 104,448,000 B
constexpr int NW7 = 7;                          // fallback params
constexpr int NCT7 = 250;
}

using h8 = __attribute__((ext_vector_type(8))) _Float16;

__device__ __forceinline__ float fexp2(float x){ return __builtin_amdgcn_exp2f(x); }
__device__ __forceinline__ float flog2(float x){ return __builtin_amdgcn_logf(x); }

__device__ __forceinline__ float wave_shr1(float x) {
  int v = __builtin_amdgcn_update_dpp(0, __builtin_bit_cast(int, x),
                                      0x138 /*WAVE_SHR1*/, 0xf, 0xf, true);
  return __builtin_bit_cast(float, v);
}
__device__ __forceinline__ int wave_shr1_i(int x) {
  return __builtin_amdgcn_update_dpp(0, x, 0x138, 0xf, 0xf, true);
}

// ---------------- gather pass: G[b][c][k][j] = fp16(exp(lp[b][1+8c+j][col_k]))
// Block = (tile of 64 t-values = 8 chunks) x batch, 512 threads.
// Phase 1: stage 64 rows of lp in LDS (stride 257). Phase 2: lane =
// (kk = lane>>3, j = lane&7); each wave handles (k-group, chunk) pairs:
// one LDS read + exp2 + contiguous 128B fp16 store per lane per iter;
// 51 independent iterations pipeline freely.
__global__ __launch_bounds__(512)
void ctc_gather_kernel(const float* __restrict__ logp,
                       const int* __restrict__ targets,
                       _Float16* __restrict__ G)
{
  const int tile = blockIdx.x;            // 32 tiles
  const int b    = blockIdx.y;
  const int tid  = threadIdx.x;
  const int i0   = tile * 64;             // t-range [i0+1, i0+64]
  const float* lp = logp + (size_t)b * T * V;
  const int*   tg = targets + (size_t)b * S;

  __shared__ float ls[64 * 257];          // 64.25 KB
  __shared__ int   tgs[S];

  for (int f = tid; f < 64 * 64; f += 512) {
    const int row = f >> 6, c4 = f & 63;
    int t = i0 + 1 + row; if (t > T - 1) t = T - 1;
    float4 v = ((const float4*)(lp + (size_t)t * V))[c4];
    float* d = &ls[row * 257 + c4 * 4];
    d[0] = v.x; d[1] = v.y; d[2] = v.z; d[3] = v.w;
  }
  for (int k = tid; k < S; k += 512) tgs[k] = tg[k];
  __syncthreads();

  const int w    = tid >> 6;
  const int lane = tid & 63;
  const int kk   = lane >> 3;             // k sub-index 0..7
  const int j    = lane & 7;              // t within chunk
  _Float16* gb = G + (size_t)b * NCTP * KP * 8;

  // work items: 51 k-groups x 8 chunks = 408, strided over 8 waves
  for (int idx = w; idx < 408; idx += 8) {
    const int kg = idx >> 3;              // k-group 0..50
    const int cc = idx & 7;               // chunk within tile
    const int c  = tile * 8 + cc;
    if (c >= NCTP) continue;
    int k = kg * 8 + kk;
    const int e = (k < S) ? tgs[k] : 1;   // rows 400..407: blank/pad
    const float p = fexp2(ls[(cc * 8 + j) * 257 + e] * LOG2E);
    gb[((size_t)c * KP + k) * 8 + j] = (_Float16)p;
  }
}

// ---------------- main: 8 waves per chain, 2 states/lane, prob domain -------
__global__ __launch_bounds__(512)
void ctc_alpha8_kernel(const float* __restrict__ logp,
                       const int* __restrict__ targets,
                       const int* __restrict__ input_len,
                       const int* __restrict__ target_len,
                       const _Float16* __restrict__ G,
                       float* __restrict__ out)
{
  const int b    = blockIdx.x;
  const int tid  = threadIdx.x;
  const int w    = tid >> 6;
  const int lane = tid & 63;
  const bool lane0 = (lane == 0);
  const float* __restrict__ lp = logp + (size_t)b * T * V;
  const int il = input_len[b];
  const int tl = target_len[b];

  __shared__ float bnd[7][NCTP * BSTR];   // 84 KB boundary streams
  __shared__ int   cnt[7];
  __shared__ float afin[1024];

  if (tid < 7) cnt[tid] = 0;

  // lane owns states {2g, 2g+1}, g = tid; token index = g
  const int* tg = targets + (size_t)b * S;
  const int k1 = (tid < S) ? tid : (S - 1);
  const int e1 = tg[k1];
  const float sk1 = (k1 == 0 || e1 != tg[k1 - 1]) ? 1.0f : 0.0f;

  const _Float16* Gb = G + (size_t)b * NCTP * KP * 8;
  const size_t tokOff = (size_t)k1 * 8;   // contiguous across lanes
  const size_t blkOff = (size_t)400 * 8;  // wave-uniform

  __syncthreads();   // cnt visible

  float a0 = 0.0f, a1 = 0.0f;
  int   E  = 0;
  if (tid == 0) {
    a0 = fexp2(lp[1]  * LOG2E);
    a1 = fexp2(lp[e1] * LOG2E);
  }

  // preload chunk 0
  h8 ha = *(const h8*)(Gb + tokOff);
  h8 hk = *(const h8*)(Gb + blkOff);

  const int NCH = (il - 1 + CHK - 1) / CHK;   // <= 250
  for (int c = 0; c < NCH; ++c) {
    float pa[CHK], pk[CHK];
    #pragma unroll
    for (int i = 0; i < CHK; ++i) { pa[i] = (float)ha[i]; pk[i] = (float)hk[i]; }

    // prefetch next chunk (clamped; 16 lines + 1 line per wave)
    {
      const int c2 = (c + 1 < NCTP) ? (c + 1) : (NCTP - 1);
      const size_t base = (size_t)c2 * KP * 8;
      ha = *(const h8*)(Gb + base + tokOff);
      hk = *(const h8*)(Gb + base + blkOff);
    }

    // consume boundary chunk
    float bq[CHK];
    int Ep = 0;
    if (w > 0) {
      while (__hip_atomic_load(&cnt[w - 1], __ATOMIC_ACQUIRE,
                               __HIP_MEMORY_SCOPE_WORKGROUP) < c + 1)
        __builtin_amdgcn_s_sleep(1);
      const float* src = &bnd[w - 1][c * BSTR];
      float4 q0 = *(const float4*)(src);
      float4 q1 = *(const float4*)(src + 4);
      bq[0]=q0.x; bq[1]=q0.y; bq[2]=q0.z; bq[3]=q0.w;
      bq[4]=q1.x; bq[5]=q1.y; bq[6]=q1.z; bq[7]=q1.w;
      Ep = __float_as_int(src[8]);
    } else {
      #pragma unroll
      for (int i = 0; i < CHK; ++i) bq[i] = 0.0f;
    }

    // exponent bookkeeping: 1 shfl + 3 DPP (was 4 shfl)
    const float mz  = fmaxf(a0, a1);
    const int   E8  = __shfl_up(E, 8);
    const int   E1o = wave_shr1_i(E);
    const int   E9  = wave_shr1_i(E8);
    const float mz1 = wave_shr1(mz);
    if (mz == 0.0f) E = (lane < 8) ? Ep : E8;            // pre-adopt scale
    int E1 = (mz1 == 0.0f) ? ((lane <= 8) ? Ep : E9) : E1o;
    if (lane0) E1 = (w == 0) ? E : Ep;
    int d = E1 - E; d = d > 126 ? 126 : (d < -126 ? -126 : d);
    const float f = ldexpf(1.0f, d);
    const float a1s = a1;

    float pub[CHK];
    #pragma unroll
    for (int i = 0; i < CHK; ++i) {
      const int t = 1 + c * CHK + i;
      if (t < il) {                        // wave-uniform freeze predicate
        float hl = wave_shr1(a1);
        hl = lane0 ? bq[i] : hl;
        hl *= f;
        float s01 = a1 + a0;
        a1 = __builtin_fmaf(hl, sk1, s01) * pa[i];
        a0 = (a0 + hl) * pk[i];
      }
      pub[i] = a1;
    }

    // publish boundary (in this chunk's scale E) + release
    if (w < 7 && lane == 63) {
      float* dst = &bnd[w][c * BSTR];
      *(float4*)(dst)     = make_float4(a1s, pub[0], pub[1], pub[2]);
      *(float4*)(dst + 4) = make_float4(pub[3], pub[4], pub[5], pub[6]);
      dst[8] = __int_as_float(E);
      __hip_atomic_store(&cnt[w], c + 1, __ATOMIC_RELEASE,
                         __HIP_MEMORY_SCOPE_WORKGROUP);
    }

    // renormalize per lane
    {
      float m2 = fmaxf(a0, a1);
      int k = 0;
      (void)frexpf(m2, &k);                // m2==0 -> k=0
      a0 = ldexpf(a0, -k);
      a1 = ldexpf(a1, -k);
      E += k;
    }
  }

  afin[2 * tid]     = flog2(a0) + (float)E;
  afin[2 * tid + 1] = flog2(a1) + (float)E;
  __syncthreads();

  if (tid == 0) {
    const float x = afin[2 * tl];
    const float y = afin[2 * tl - 1];
    const float m = fmaxf(x, y);
    const float ll = (m + flog2(fexp2(x - m) + fexp2(y - m))) * LN2;
    float loss = -ll;
    if (!(loss < 1e29f)) loss = 0.0f;
    atomicAdd(out, loss / ((float)tl * (float)B));
  }
}

// ---------------- fallback: round-6 kernel (validated), if ws too small -----
__global__ __launch_bounds__(NW7 * 64)
void ctc_alpha7_kernel(const float* __restrict__ logp,
                       const int* __restrict__ targets,
                       const int* __restrict__ input_len,
                       const int* __restrict__ target_len,
                       float* __restrict__ out)
{
  const int b    = blockIdx.x;
  const int tid  = threadIdx.x;
  const int w    = tid >> 6;
  const int lane = tid & 63;
  const bool lane0 = (lane == 0);
  const float* __restrict__ lp = logp + (size_t)b * T * V;
  const int il = input_len[b];
  const int tl = target_len[b];
  const int Lb = 2 * tl + 1;

  __shared__ float bnd[NW7 - 1][NCT7 * BSTR];
  __shared__ int   cnt[NW7 - 1];
  __shared__ float pblk[T];
  __shared__ float afin[NW7 * 64 * 2];

  if (tid < NW7 - 1) cnt[tid] = 0;

  const int* tg = targets + (size_t)b * S;
  const int k1 = (tid < S) ? tid : (S - 1);
  const int e1 = tg[k1];
  const float sk1 = (k1 == 0 || e1 != tg[k1 - 1]) ? 1.0f : 0.0f;

  for (int i = tid; i < T; i += NW7 * 64) {
    int t = (i + 1 < T) ? (i + 1) : (T - 1);
    pblk[i] = fexp2(lp[(size_t)t * V + 1] * LOG2E);
  }
  __syncthreads();

  const bool active = (w * 128) < Lb;
  if (active) {
    float a0 = 0.0f, a1 = 0.0f;
    int   E  = 0;
    if (tid == 0) { a0 = fexp2(lp[1] * LOG2E); a1 = fexp2(lp[e1] * LOG2E); }

    float tokL[CHK];
    #pragma unroll
    for (int i = 0; i < CHK; ++i) tokL[i] = lp[(size_t)(1 + i) * V + e1];

    const int NCH = (il - 1 + CHK - 1) / CHK;
    for (int c = 0; c < NCH; ++c) {
      const int t0 = 1 + c * CHK;
      float tokP[CHK];
      #pragma unroll
      for (int i = 0; i < CHK; ++i) tokP[i] = fexp2(tokL[i] * LOG2E);
      float nl[CHK];
      if (c + 1 < NCT7) {
        #pragma unroll
        for (int i = 0; i < CHK; ++i) {
          int tt = t0 + CHK + i; if (tt > T - 1) tt = T - 1;
          nl[i] = lp[(size_t)tt * V + e1];
        }
      }
      float pbk[CHK];
      {
        float4 q0 = *(const float4*)&pblk[c * CHK];
        float4 q1 = *(const float4*)&pblk[c * CHK + 4];
        pbk[0]=q0.x; pbk[1]=q0.y; pbk[2]=q0.z; pbk[3]=q0.w;
        pbk[4]=q1.x; pbk[5]=q1.y; pbk[6]=q1.z; pbk[7]=q1.w;
      }
      float bq[CHK];
      int Ep = 0;
      if (w > 0) {
        while (__hip_atomic_load(&cnt[w - 1], __ATOMIC_ACQUIRE,
                                 __HIP_MEMORY_SCOPE_WORKGROUP) < c + 1)
          __builtin_amdgcn_s_sleep(1);
        const float* src = &bnd[w - 1][c * BSTR];
        float4 q0 = *(const float4*)(src);
        float4 q1 = *(const float4*)(src + 4);
        bq[0]=q0.x; bq[1]=q0.y; bq[2]=q0.z; bq[3]=q0.w;
        bq[4]=q1.x; bq[5]=q1.y; bq[6]=q1.z; bq[7]=q1.w;
        Ep = __float_as_int(src[8]);
      } else {
        #pragma unroll
        for (int i = 0; i < CHK; ++i) bq[i] = 0.0f;
      }
      const float mz  = fmaxf(a0, a1);
      const int   E1o = __shfl_up(E, 1);
      const int   E8  = __shfl_up(E, 8);
      const int   E9  = __shfl_up(E, 9);
      const float mz1 = __shfl_up(mz, 1);
      if (mz == 0.0f) E = (lane < 8) ? Ep : E8;
      int E1 = (mz1 == 0.0f) ? ((lane <= 8) ? Ep : E9) : E1o;
      if (lane0) E1 = (w == 0) ? E : Ep;
      int d = E1 - E; d = d > 126 ? 126 : (d < -126 ? -126 : d);
      const float f = ldexpf(1.0f, d);
      const float a1s = a1;
      float pub[CHK];
      #pragma unroll
      for (int i = 0; i < CHK; ++i) {
        const int t = t0 + i;
        if (t < il) {
          float hl = wave_shr1(a1);
          hl = lane0 ? bq[i] : hl;
          hl *= f;
          float s01 = a1 + a0;
          a1 = __builtin_fmaf(hl, sk1, s01) * tokP[i];
          a0 = (a0 + hl) * pbk[i];
        }
        pub[i] = a1;
      }
      if (w < NW7 - 1 && lane == 63) {
        float* dst = &bnd[w][c * BSTR];
        dst[0] = a1s;
        #pragma unroll
        for (int i = 0; i < CHK - 1; ++i) dst[1 + i] = pub[i];
        dst[8] = __int_as_float(E);
        __hip_atomic_store(&cnt[w], c + 1, __ATOMIC_RELEASE,
                           __HIP_MEMORY_SCOPE_WORKGROUP);
      }
      {
        float m2 = fmaxf(a0, a1);
        int k = 0;
        (void)frexpf(m2, &k);
        a0 = ldexpf(a0, -k);
        a1 = ldexpf(a1, -k);
        E += k;
      }
      #pragma unroll
      for (int i = 0; i < CHK; ++i) tokL[i] = nl[i];
    }
    afin[2 * tid]     = flog2(a0) + (float)E;
    afin[2 * tid + 1] = flog2(a1) + (float)E;
  }
  __syncthreads();

  if (tid == 0) {
    const float x = afin[2 * tl];
    const float y = afin[2 * tl - 1];
    const float m = fmaxf(x, y);
    const float ll = (m + flog2(fexp2(x - m) + fexp2(y - m))) * LN2;
    float loss = -ll;
    if (!(loss < 1e29f)) loss = 0.0f;
    atomicAdd(out, loss / ((float)tl * (float)B));
  }
}

__global__ void ctc_zero_kernel(float* __restrict__ out) { out[0] = 0.0f; }

extern "C" void kernel_launch(void* const* d_in, const int* in_sizes, int n_in,
                              void* d_out, int out_size, void* d_ws, size_t ws_size,
                              hipStream_t stream) {
  const float* logp    = (const float*)d_in[0];
  const int*   targets = (const int*)d_in[1];
  const int*   il      = (const int*)d_in[2];
  const int*   tl      = (const int*)d_in[3];
  float* out = (float*)d_out;

  ctc_zero_kernel<<<1, 1, 0, stream>>>(out);
  if (ws_size >= GBYTES) {
    _Float16* G = (_Float16*)d_ws;
    ctc_gather_kernel<<<dim3(32, B), 512, 0, stream>>>(logp, targets, G);
    ctc_alpha8_kernel<<<B, 512, 0, stream>>>(logp, targets, il, tl, G, out);
  } else {
    ctc_alpha7_kernel<<<B, NW7 * 64, 0, stream>>>(logp, targets, il, tl, out);
  }
}